// Round 4
// baseline (562.594 us; speedup 1.0000x reference)
//
#include <hip/hip_runtime.h>

#define GLOBAL_AS __attribute__((address_space(1)))
#define LDS_AS    __attribute__((address_space(3)))

typedef short bf16x8 __attribute__((ext_vector_type(8)));
typedef float f32x4  __attribute__((ext_vector_type(4)));
typedef float f32x16 __attribute__((ext_vector_type(16)));

// Problem shape (fixed by setup_inputs)
#define M_DIM 8192     // B*S = 4*2048
#define N_DIM 4096     // DOUT
#define K_DIM 4096     // DIN  (lora folded into weights)
#define R_DIM 16

__constant__ float NF4C[16] = {
    -1.0f, -0.6961928009986877f, -0.5250730514526367f, -0.39491748809814453f,
    -0.28444138169288635f, -0.18477343022823334f, -0.09105003625154495f, 0.0f,
    0.07958029955625534f, 0.16093020141124725f, 0.24611230194568634f,
    0.33791524171829224f, 0.44070982933044434f, 0.5626170039176941f,
    0.7229568362236023f, 1.0f};

__device__ __forceinline__ unsigned short f2bf(float f) {
    unsigned int u = __float_as_uint(f);
    u += 0x7fffu + ((u >> 16) & 1u);   // round-to-nearest-even
    return (unsigned short)(u >> 16);
}

// ---- merged prep: blocks [0,16384) dequant+fold, [16384,24576) x convert ----
// dequant: wq = bf16( NF4[c]*absmax + 2*B*A ); n block-uniform, A L2-resident.
__global__ __launch_bounds__(256) void prep_kernel(
        const float4* __restrict__ x4, const int4* __restrict__ codes4,
        const float* __restrict__ absmax, const float4* __restrict__ loraB4,
        const float4* __restrict__ A4, unsigned short* __restrict__ xb,
        unsigned short* __restrict__ wq) {
    const int tid = threadIdx.x;
    if (blockIdx.x >= 16384) {   // x fp32 -> bf16: 8192 blocks, 4 float4/thread
        const int b = blockIdx.x - 16384;
#pragma unroll
        for (int j = 0; j < 4; ++j) {
            const int idx = b * 1024 + j * 256 + tid;
            float4 v = x4[idx];
            ushort4 o;
            o.x = f2bf(v.x); o.y = f2bf(v.y); o.z = f2bf(v.z); o.w = f2bf(v.w);
            *(ushort4*)(xb + (size_t)idx * 4) = o;
        }
        return;
    }
    const int idx = blockIdx.x * 256 + tid;   // int4 index, 4096*1024
    const int n = idx >> 10;
    const int k4 = idx & 1023;
    const float am = absmax[n * 64 + (k4 >> 4)];
    int4 c = codes4[idx];
    float4 b[4];
#pragma unroll
    for (int j = 0; j < 4; ++j) b[j] = loraB4[n * 4 + j];
    float bax = 0.f, bay = 0.f, baz = 0.f, baw = 0.f;
#pragma unroll
    for (int r = 0; r < 16; ++r) {
        const float br = (r & 2) ? ((r & 1) ? b[r >> 2].w : b[r >> 2].z)
                                 : ((r & 1) ? b[r >> 2].y : b[r >> 2].x);
        float4 av = A4[r * 1024 + k4];
        bax += br * av.x; bay += br * av.y; baz += br * av.z; baw += br * av.w;
    }
    ushort4 o;
    o.x = f2bf(NF4C[c.x] * am + 2.0f * bax);
    o.y = f2bf(NF4C[c.y] * am + 2.0f * bay);
    o.z = f2bf(NF4C[c.z] * am + 2.0f * baz);
    o.w = f2bf(NF4C[c.w] * am + 2.0f * baw);
    *(ushort4*)(wq + (size_t)n * K_DIM + k4 * 4) = o;
}

// ---- main GEMM: 256x256 tile, BK=64, 8 waves (2M x 4N), 8-phase counted-vmcnt
// Now on v_mfma_f32_32x32x16_bf16 (4060 FLOP/cy pipe vs 3378 for 16x16x32).
// LDS 128KB: A[2dbuf][2kh][256 rows][32 shorts] at 0, B same at 32768 (shorts).
// Swizzle: 16B-chunk c ^= (row>>1)&3 within 64B rows; 32x32 frag reads stay
// perfectly bank-balanced (8 lanes per 16B bank-group). Stage/vmcnt schedule
// identical to the verified round-2 kernel.
#define STG(gptr, ldsoff)                                                   \
    __builtin_amdgcn_global_load_lds((const GLOBAL_AS void*)(gptr),         \
                                     (LDS_AS void*)(smem + (ldsoff)), 16, 0, 0)
#define STAGE_A(d, kh, kt) do {                                             \
    STG(gA + (size_t)(kt) * 64 + (kh) * 32,                                 \
        (d) * 16384 + (kh) * 8192 + wave * 512);                            \
    STG(gA + (size_t)128 * K_DIM + (size_t)(kt) * 64 + (kh) * 32,           \
        (d) * 16384 + (kh) * 8192 + 4096 + wave * 512); } while (0)
#define STAGE_B(d, kh, kt) do {                                             \
    STG(gB + (size_t)(kt) * 64 + (kh) * 32,                                 \
        32768 + (d) * 16384 + (kh) * 8192 + wave * 512);                    \
    STG(gB + (size_t)128 * K_DIM + (size_t)(kt) * 64 + (kh) * 32,           \
        32768 + (d) * 16384 + (kh) * 8192 + 4096 + wave * 512); } while (0)
#define NOPX ((void)0)
#define VMCNT6 asm volatile("s_waitcnt vmcnt(6)" ::: "memory")
#define VMCNT0 asm volatile("s_waitcnt vmcnt(0)" ::: "memory")

// phase (d, kh, mig): reads af for m-frags {mig*2, mig*2+1} x 2 ksteps;
// bfr (2 n-frags x 2 ksteps) loaded at mig==0, reused at mig==1.
// ks1 chunk = ks0 chunk ^ 2  ->  short-offset ^ 16.
#define PHASE(d, kh, mig, STAGE_STMT, VM_STMT) do {                         \
    const int rb_ = (d) * 16384 + (kh) * 8192;                              \
    bf16x8 af_[2][2];                                                       \
    _Pragma("unroll")                                                       \
    for (int mi_ = 0; mi_ < 2; ++mi_) {                                     \
        const int a0_ = rb_ + aoff + ((mig) * 2 + mi_) * 1024;              \
        af_[mi_][0] = *(const bf16x8*)(smem + a0_);                         \
        af_[mi_][1] = *(const bf16x8*)(smem + (a0_ ^ 16));                  \
    }                                                                       \
    if ((mig) == 0) {                                                       \
        _Pragma("unroll")                                                   \
        for (int ni_ = 0; ni_ < 2; ++ni_) {                                 \
            const int b0_ = rb_ + boff + ni_ * 1024;                        \
            bfr[ni_][0] = *(const bf16x8*)(smem + b0_);                     \
            bfr[ni_][1] = *(const bf16x8*)(smem + (b0_ ^ 16));              \
        }                                                                   \
    }                                                                       \
    STAGE_STMT;                                                             \
    __builtin_amdgcn_s_barrier();                                           \
    asm volatile("s_waitcnt lgkmcnt(0)" ::: "memory");                      \
    __builtin_amdgcn_sched_barrier(0);                                      \
    __builtin_amdgcn_s_setprio(1);                                          \
    _Pragma("unroll")                                                       \
    for (int ks_ = 0; ks_ < 2; ++ks_)                                       \
        _Pragma("unroll")                                                   \
        for (int mi_ = 0; mi_ < 2; ++mi_)                                   \
            _Pragma("unroll")                                               \
            for (int ni_ = 0; ni_ < 2; ++ni_)                               \
                acc[(mig) * 2 + mi_][ni_] =                                 \
                    __builtin_amdgcn_mfma_f32_32x32x16_bf16(                \
                        af_[mi_][ks_], bfr[ni_][ks_],                       \
                        acc[(mig) * 2 + mi_][ni_], 0, 0, 0);                \
    __builtin_amdgcn_s_setprio(0);                                          \
    VM_STMT;                                                                \
    __builtin_amdgcn_s_barrier();                                           \
} while (0)

__global__ __launch_bounds__(512) void gemm_kernel(
        const unsigned short* __restrict__ xb,
        const unsigned short* __restrict__ wq,
        float* __restrict__ out) {
    __shared__ __align__(16) unsigned short smem[65536];   // 128 KiB
    const int tid = threadIdx.x;
    const int wave = tid >> 6, lane = tid & 63;

    // XCD-aware swizzle over 512 blocks (16 n-tiles x 32 m-tiles); 512%8==0
    const int bid = blockIdx.y * 16 + blockIdx.x;
    const int swz = (bid & 7) * 64 + (bid >> 3);
    const int m0 = (swz >> 4) * 256;
    const int n0 = (swz & 15) * 256;

    // staging: thread covers row 16*wave + (lane>>2), swizzled 16B chunk
    const int schunk = ((lane & 3) ^ ((lane >> 3) & 3)) * 8;
    const unsigned short* gA =
        xb + (size_t)(m0 + wave * 16 + (lane >> 2)) * K_DIM + schunk;
    const unsigned short* gB =
        wq + (size_t)(n0 + wave * 16 + (lane >> 2)) * K_DIM + schunk;

    // fragment read bases (32x32x16: lane -> row l&31, k-half l>>5)
    const int wr = wave >> 2, wc = wave & 3;
    const int l31 = lane & 31, c0 = lane >> 5;
    const int key = (l31 >> 1) & 3;
    const int aoff = (wr * 128 + l31) * 32 + ((c0 ^ key) * 8);
    const int boff = 32768 + (wc * 64 + l31) * 32 + ((c0 ^ key) * 8);

    f32x16 acc[4][2] = {};
    bf16x8 bfr[2][2];

    // prologue: t0 {A0,B0,A1,B1}, t1 {B0,A0,B1}; vmcnt(6) -> t0 fully landed
    STAGE_A(0, 0, 0); STAGE_B(0, 0, 0); STAGE_A(0, 1, 0); STAGE_B(0, 1, 0);
    STAGE_B(1, 0, 1); STAGE_A(1, 0, 1); STAGE_B(1, 1, 1);
    VMCNT6;
    __builtin_amdgcn_s_barrier();

#pragma unroll 1
    for (int kt = 0; kt < 62; kt += 2) {
        // tile kt (buf0)
        PHASE(0, 0, 0, STAGE_A(1, 1, kt + 1), NOPX);
        PHASE(0, 0, 1, STAGE_B(0, 0, kt + 2), NOPX);
        PHASE(0, 1, 0, STAGE_A(0, 0, kt + 2), NOPX);
        PHASE(0, 1, 1, STAGE_B(0, 1, kt + 2), VMCNT6);
        // tile kt+1 (buf1)
        PHASE(1, 0, 0, STAGE_A(0, 1, kt + 2), NOPX);
        PHASE(1, 0, 1, STAGE_B(1, 0, kt + 3), NOPX);
        PHASE(1, 1, 0, STAGE_A(1, 0, kt + 3), NOPX);
        PHASE(1, 1, 1, STAGE_B(1, 1, kt + 3), VMCNT6);
    }
    // tile 62 (buf0): only t63 A-kh1 left to stage; drain before last tile
    PHASE(0, 0, 0, STAGE_A(1, 1, 63), NOPX);
    PHASE(0, 0, 1, NOPX, NOPX);
    PHASE(0, 1, 0, NOPX, NOPX);
    PHASE(0, 1, 1, NOPX, VMCNT0);
    // tile 63 (buf1): no stages
    PHASE(1, 0, 0, NOPX, NOPX);
    PHASE(1, 0, 1, NOPX, NOPX);
    PHASE(1, 1, 0, NOPX, NOPX);
    PHASE(1, 1, 1, NOPX, NOPX);

    // epilogue: 32x32 C/D layout col=lane&31, row=(reg&3)+8*(reg>>2)+4*(lane>>5)
    const int col0 = n0 + wc * 64 + l31;
    const int row0 = m0 + wr * 128 + c0 * 4;
#pragma unroll
    for (int mi = 0; mi < 4; ++mi)
#pragma unroll
        for (int ni = 0; ni < 2; ++ni)
#pragma unroll
            for (int r = 0; r < 16; ++r) {
                const int row = row0 + mi * 32 + (r & 3) + 8 * (r >> 2);
                out[(size_t)row * N_DIM + col0 + ni * 32] = acc[mi][ni][r];
            }
}

extern "C" void kernel_launch(void* const* d_in, const int* in_sizes, int n_in,
                              void* d_out, int out_size, void* d_ws, size_t ws_size,
                              hipStream_t stream) {
    const float* x      = (const float*)d_in[0];
    const int*   codes  = (const int*)d_in[1];
    const float* absmax = (const float*)d_in[2];
    const float* loraA  = (const float*)d_in[3];
    const float* loraB  = (const float*)d_in[4];
    float* out = (float*)d_out;

    unsigned short* xb = (unsigned short*)d_ws;            // [8192][4096] bf16
    unsigned short* wq = xb + (size_t)M_DIM * K_DIM;       // [4096][4096] bf16

    prep_kernel<<<24576, 256, 0, stream>>>(
        (const float4*)x, (const int4*)codes, absmax, (const float4*)loraB,
        (const float4*)loraA, xb, wq);

    dim3 grid(N_DIM / 256, M_DIM / 256);   // 16 x 32
    gemm_kernel<<<grid, 512, 0, stream>>>(xb, wq, out);
}